// Round 1
// baseline (666.608 us; speedup 1.0000x reference)
//
#include <hip/hip_runtime.h>
#include <math.h>

// Problem constants (from reference)
constexpr int BATCH = 4096;
constexpr int T  = 200;
constexpr int H  = 64;    // head dim; D_IN = 4*H = 256
constexpr int D1 = 80;
constexpr int D2 = 40;

__device__ __forceinline__ float fast_sigmoid(float x) {
    // 1/(1+exp(-x)) via hw exp + fast rcp (~1 ulp, fine for 2%-of-absmax tol)
    return __builtin_amdgcn_rcpf(1.0f + __expf(-x));
}

// One block per batch row b. 256 threads = 4 waves.
// Phase A: build per-b effective layer-1 weights:
//   x = [q, k, q-k, q*k]  =>  x@W1 = qpart(b) + k @ Weff(b)
//   qpart[j] = b1[j] + sum_i q_i*(W1[i][j] + W1[128+i][j])
//   Weff[i][j] = W1[64+i][j] - W1[128+i][j] + q_i*W1[192+i][j]
// Phase B: thread t computes the MLP score for position t (keys row in VGPRs,
//   Weff^T rows broadcast from LDS).
// Phase C: block softmax (mask t >= len, scale 1/8).
// Phase D: out[b][h] = sum_t att_t * K[t][h], coalesced global re-read.
__global__ __launch_bounds__(256, 2) void din_fused(
    const float* __restrict__ q_g, const float* __restrict__ keys_g,
    const int* __restrict__ len_g, const float* __restrict__ W1,
    const float* __restrict__ b1g, const float* __restrict__ W2g,
    const float* __restrict__ b2g, const float* __restrict__ Wdg,
    const float* __restrict__ bdg, float* __restrict__ out)
{
    __shared__ __align__(16) float sQ[H];
    __shared__ __align__(16) float sQpart[D1];
    __shared__ __align__(16) float sWeffT[D1][H];   // [j][i], rows 256B -> ds_read_b128 ok
    __shared__ __align__(16) float sW2[D1 * D2];    // row-major [j][j2]
    __shared__ __align__(16) float sB2[D2];
    __shared__ __align__(16) float sWd[D2];
    __shared__ __align__(16) float sScore[T];
    __shared__ __align__(16) float sRed[8];
    __shared__ __align__(16) float sPart[4][H];

    const int b    = blockIdx.x;
    const int tid  = threadIdx.x;
    const int lane = tid & 63;
    const int wave = tid >> 6;
    const int len  = len_g[b];

    // ---- Phase A: stage weights ----
    if (tid < H) sQ[tid] = q_g[b * H + tid];
    for (int idx = tid; idx < D1 * D2; idx += 256) sW2[idx] = W2g[idx];
    if (tid < D2) { sB2[tid] = b2g[tid]; sWd[tid] = Wdg[tid]; }
    __syncthreads();

    if (tid < D1) {
        float acc = b1g[tid];
        #pragma unroll 8
        for (int i = 0; i < H; ++i)
            acc += sQ[i] * (W1[i * D1 + tid] + W1[(128 + i) * D1 + tid]);
        sQpart[tid] = acc;
    }
    for (int idx = tid; idx < D1 * H; idx += 256) {
        const int j = idx % D1;          // consecutive tid -> consecutive j: coalesced W1 reads
        const int i = idx / D1;
        sWeffT[j][i] = W1[(64 + i) * D1 + j] - W1[(128 + i) * D1 + j]
                     + sQ[i] * W1[(192 + i) * D1 + j];
    }
    __syncthreads();

    // ---- Phase B: per-position MLP score ----
    float score = -INFINITY;
    const int t = tid;
    if (t < T) {
        const float4* krow4 = (const float4*)(keys_g + ((size_t)b * T + t) * H);
        float kreg[H];
        #pragma unroll
        for (int i = 0; i < H / 4; ++i) {
            float4 v = krow4[i];
            kreg[4 * i + 0] = v.x; kreg[4 * i + 1] = v.y;
            kreg[4 * i + 2] = v.z; kreg[4 * i + 3] = v.w;
        }
        float h2[D2];
        #pragma unroll
        for (int j2 = 0; j2 < D2; ++j2) h2[j2] = sB2[j2];

        for (int j = 0; j < D1; ++j) {     // rolled: ~135 instr body, h2[] stays in regs
            float a0 = 0.f, a1 = 0.f, a2 = 0.f, a3 = 0.f;
            #pragma unroll
            for (int i = 0; i < H; i += 4) {
                a0 += kreg[i + 0] * sWeffT[j][i + 0];
                a1 += kreg[i + 1] * sWeffT[j][i + 1];
                a2 += kreg[i + 2] * sWeffT[j][i + 2];
                a3 += kreg[i + 3] * sWeffT[j][i + 3];
            }
            const float h1 = fast_sigmoid(sQpart[j] + ((a0 + a1) + (a2 + a3)));
            #pragma unroll
            for (int j2 = 0; j2 < D2; ++j2) h2[j2] += h1 * sW2[j * D2 + j2];
        }
        float s = bdg[0];
        #pragma unroll
        for (int j2 = 0; j2 < D2; ++j2) s += fast_sigmoid(h2[j2]) * sWd[j2];
        score = (t < len) ? s * 0.125f : -INFINITY;   // mask then scale by 1/sqrt(64)
    }

    // ---- Phase C: block softmax over T ----
    float m = score;   // inactive threads contribute -inf
    #pragma unroll
    for (int off = 32; off >= 1; off >>= 1)
        m = fmaxf(m, __shfl_xor(m, off, 64));
    if (lane == 0) sRed[wave] = m;
    __syncthreads();
    m = fmaxf(fmaxf(sRed[0], sRed[1]), fmaxf(sRed[2], sRed[3]));

    float e = 0.0f;
    if (t < T && t < len) e = __expf(score - m);
    float l = e;
    #pragma unroll
    for (int off = 32; off >= 1; off >>= 1)
        l += __shfl_xor(l, off, 64);
    if (lane == 0) sRed[4 + wave] = l;
    if (t < T) sScore[t] = e;              // unnormalized weights (0 for masked)
    __syncthreads();
    l = sRed[4] + sRed[5] + sRed[6] + sRed[7];
    const float inv_l = __builtin_amdgcn_rcpf(l);

    // ---- Phase D: weighted sum of keys ----
    const int h = tid & 63;
    const int c = tid >> 6;                 // 4 t-chunks of 50
    float p = 0.0f;
    for (int t2 = c * 50; t2 < c * 50 + 50; ++t2)
        p += sScore[t2] * keys_g[((size_t)b * T + t2) * H + h];   // coalesced
    sPart[c][h] = p;
    __syncthreads();
    if (tid < H)
        out[b * H + tid] = (sPart[0][tid] + sPart[1][tid] + sPart[2][tid] + sPart[3][tid]) * inv_l;
}

extern "C" void kernel_launch(void* const* d_in, const int* in_sizes, int n_in,
                              void* d_out, int out_size, void* d_ws, size_t ws_size,
                              hipStream_t stream) {
    const float* q    = (const float*)d_in[0];
    const float* keys = (const float*)d_in[1];
    const int*   lens = (const int*)d_in[2];
    const float* W1   = (const float*)d_in[3];
    const float* b1   = (const float*)d_in[4];
    const float* W2   = (const float*)d_in[5];
    const float* b2   = (const float*)d_in[6];
    const float* Wd   = (const float*)d_in[7];
    const float* bd   = (const float*)d_in[8];
    float* outp = (float*)d_out;

    din_fused<<<BATCH, 256, 0, stream>>>(q, keys, lens, W1, b1, W2, b2, Wd, bd, outp);
}

// Round 2
// 424.293 us; speedup vs baseline: 1.5711x; 1.5711x over previous
//
#include <hip/hip_runtime.h>
#include <math.h>

// DIN-style sequence attention, MFMA version.
// Scores = MLP([q,k,q-k,q*k]) collapses to: sigmoid-MLP over (qpart + K @ Weff)
// where Weff/qpart are per-batch-row rank-collapsed from W1 (exact algebra).
// Layers 1-2 run on matrix cores (bf16, fp32 accum); layer 3 + softmax +
// weighted key-sum stay on VALU. bd is dropped: constant score shift cancels
// in softmax.

constexpr int BATCH = 4096;
constexpr int T  = 200;
constexpr int H  = 64;     // D_IN = 4H = 256
constexpr int D1 = 80;
constexpr int D2 = 40;
constexpr int MROW = 208;  // 13 M-tiles of 16
constexpr int KS1  = 72;   // sKb / sWe row stride (64 + 8 pad): 2-way banks = free
constexpr int KS2  = 104;  // sH1 / sW2T row stride (96 + 8 pad)

typedef __attribute__((ext_vector_type(8))) __bf16 bf16x8;
typedef __attribute__((ext_vector_type(4))) float  floatx4;

__device__ __forceinline__ unsigned short f2bf(float f) {  // RNE, no NaN inputs
    union { float f; unsigned u; } v; v.f = f;
    unsigned r = v.u + 0x7fffu + ((v.u >> 16) & 1u);
    return (unsigned short)(r >> 16);
}
__device__ __forceinline__ float bf2f(unsigned short s) {
    union { unsigned u; float f; } v; v.u = ((unsigned)s) << 16;
    return v.f;
}
__device__ __forceinline__ float fsig(float x) {
    return __builtin_amdgcn_rcpf(1.0f + __expf(-x));
}
#define MFMA16(a, b, c) __builtin_amdgcn_mfma_f32_16x16x32_bf16((a), (b), (c), 0, 0, 0)

__global__ __launch_bounds__(256, 2) void din_mfma(
    const float* __restrict__ q_g, const float* __restrict__ keys_g,
    const int* __restrict__ len_g, const float* __restrict__ W1,
    const float* __restrict__ b1g, const float* __restrict__ W2g,
    const float* __restrict__ b2g, const float* __restrict__ Wdg,
    const float* __restrict__ bdg, float* __restrict__ out)
{
    __shared__ __align__(16) unsigned short sKb[MROW * KS1];   // K bf16, rows>=200 zero
    __shared__ __align__(16) unsigned short sWe[D1 * KS1];     // WeffT[n][k], bf16
    __shared__ __align__(16) unsigned short sW2T[48 * KS2];    // W2T[n][k] zero-padded
    __shared__ __align__(16) unsigned short sH1[4 * 16 * KS2]; // per-wave H1 tile
    __shared__ __align__(16) float sS[MROW];                   // raw scores -> exp weights
    __shared__ __align__(16) float sQ[H];
    __shared__ __align__(16) float sQp[D1];
    __shared__ __align__(16) float sB2[48];
    __shared__ __align__(16) float sWd[48];
    __shared__ __align__(16) float sRed[8];
    __shared__ __align__(16) float sPart[8][H];

    const int b    = blockIdx.x;
    const int tid  = threadIdx.x;
    const int lane = tid & 63;
    const int wave = tid >> 6;
    const int quad = lane >> 4;
    const int col  = lane & 15;
    const int len  = len_g[b];

    // ---- Phase A1: stage q, K(bf16), W2T(bf16), biases; zero H1 k-pad ----
    if (tid < H) sQ[tid] = q_g[b * H + tid];

    const float4* keys4 = (const float4*)keys_g;
    for (int idx = tid; idx < MROW * 16; idx += 256) {
        const int row = idx >> 4, c4 = idx & 15;
        float4 v = make_float4(0.f, 0.f, 0.f, 0.f);
        if (row < T) v = keys4[((size_t)b * T + row) * 16 + c4];
        ushort4 u;
        u.x = f2bf(v.x); u.y = f2bf(v.y); u.z = f2bf(v.z); u.w = f2bf(v.w);
        *(ushort4*)&sKb[row * KS1 + c4 * 4] = u;
    }
    for (int idx = tid; idx < 48 * KS2; idx += 256) {
        const int n = idx / KS2, k = idx % KS2;
        const float v = (n < D2 && k < D1) ? W2g[k * D2 + n] : 0.f;
        sW2T[idx] = f2bf(v);
    }
    if (tid < 48) {
        sB2[tid] = (tid < D2) ? b2g[tid] : 0.f;
        sWd[tid] = (tid < D2) ? Wdg[tid] : 0.f;
    }
    for (int idx = tid; idx < 4 * 16 * 24; idx += 256) {       // H1 cols 80..103 = 0
        const int r = idx / 24, k = 80 + idx % 24;
        sH1[r * KS2 + k] = 0;
    }
    __syncthreads();

    // ---- layer-2 B fragments (W2T staged) — overlaps Weff latency ----
    bf16x8 B2f[9];
    #pragma unroll
    for (int n = 0; n < 3; ++n)
        #pragma unroll
        for (int ks = 0; ks < 3; ++ks)
            B2f[n * 3 + ks] = *(const bf16x8*)&sW2T[(n * 16 + col) * KS2 + ks * 32 + quad * 8];

    // ---- Phase A2: per-b Weff + qpart (exact collapse of concat-layer1) ----
    if (tid < D1) {
        const int j = tid;
        float qp = b1g[j];
        #pragma unroll 8
        for (int i = 0; i < H; ++i) {
            const float w0 = W1[i * D1 + j];
            const float w2 = W1[(128 + i) * D1 + j];
            qp += sQ[i] * (w0 + w2);
            const float we = W1[(64 + i) * D1 + j] - w2 + sQ[i] * W1[(192 + i) * D1 + j];
            sWe[j * KS1 + i] = f2bf(we);
        }
        sQp[j] = qp;
    }
    __syncthreads();

    // ---- layer-1 B fragments ----
    bf16x8 B1f[10];
    #pragma unroll
    for (int n = 0; n < 5; ++n)
        #pragma unroll
        for (int ks = 0; ks < 2; ++ks)
            B1f[n * 2 + ks] = *(const bf16x8*)&sWe[(n * 16 + col) * KS1 + ks * 32 + quad * 8];

    // ---- Phase B: MFMA scorer. Waves own disjoint M-tiles; no barriers. ----
    unsigned short* myH1 = &sH1[wave * 16 * KS2];
    for (int mt = wave; mt < 13; mt += 4) {
        const int Mb = mt * 16;
        // layer 1: S1 = K[16x64] @ Weff[64x80]  (A: row=lane&15, k=quad*8+j)
        const bf16x8 A0 = *(const bf16x8*)&sKb[(Mb + col) * KS1 +      quad * 8];
        const bf16x8 A1 = *(const bf16x8*)&sKb[(Mb + col) * KS1 + 32 + quad * 8];
        #pragma unroll
        for (int n = 0; n < 5; ++n) {
            floatx4 acc = {0.f, 0.f, 0.f, 0.f};
            acc = MFMA16(A0, B1f[n * 2 + 0], acc);
            acc = MFMA16(A1, B1f[n * 2 + 1], acc);
            const float qpv = sQp[n * 16 + col];
            #pragma unroll
            for (int r = 0; r < 4; ++r) {   // C/D: row=quad*4+r, col=lane&15
                const float h1 = fsig(acc[r] + qpv);
                myH1[(quad * 4 + r) * KS2 + n * 16 + col] = f2bf(h1);
            }
        }
        // layer 2: S2 = H1[16x80] @ W2[80x40] (A from wave-private LDS tile)
        const bf16x8 C0 = *(const bf16x8*)&myH1[col * KS2 +      quad * 8];
        const bf16x8 C1 = *(const bf16x8*)&myH1[col * KS2 + 32 + quad * 8];
        const bf16x8 C2 = *(const bf16x8*)&myH1[col * KS2 + 64 + quad * 8];
        float sp0 = 0.f, sp1 = 0.f, sp2 = 0.f, sp3 = 0.f;
        #pragma unroll
        for (int n = 0; n < 3; ++n) {
            floatx4 acc = {0.f, 0.f, 0.f, 0.f};
            acc = MFMA16(C0, B2f[n * 3 + 0], acc);
            acc = MFMA16(C1, B2f[n * 3 + 1], acc);
            acc = MFMA16(C2, B2f[n * 3 + 2], acc);
            const float b2v = sB2[n * 16 + col];
            const float wdv = sWd[n * 16 + col];   // zero on pad cols
            sp0 += fsig(acc[0] + b2v) * wdv;
            sp1 += fsig(acc[1] + b2v) * wdv;
            sp2 += fsig(acc[2] + b2v) * wdv;
            sp3 += fsig(acc[3] + b2v) * wdv;
        }
        // layer 3 finish: reduce over the 16 cols held across the quad's lanes
        #pragma unroll
        for (int off = 1; off <= 8; off <<= 1) {
            sp0 += __shfl_xor(sp0, off, 64);
            sp1 += __shfl_xor(sp1, off, 64);
            sp2 += __shfl_xor(sp2, off, 64);
            sp3 += __shfl_xor(sp3, off, 64);
        }
        if (col == 0) {
            sS[Mb + quad * 4 + 0] = sp0;
            sS[Mb + quad * 4 + 1] = sp1;
            sS[Mb + quad * 4 + 2] = sp2;
            sS[Mb + quad * 4 + 3] = sp3;
        }
    }
    __syncthreads();

    // ---- Phase C: block softmax over T (mask t>=len, scale 1/8) ----
    const int t = tid;
    float score = -INFINITY;
    if (t < T && t < len) score = sS[t] * 0.125f;
    float m = score;
    #pragma unroll
    for (int off = 32; off >= 1; off >>= 1)
        m = fmaxf(m, __shfl_xor(m, off, 64));
    if (lane == 0) sRed[wave] = m;
    __syncthreads();
    m = fmaxf(fmaxf(sRed[0], sRed[1]), fmaxf(sRed[2], sRed[3]));

    float e = 0.0f;
    if (t < T && t < len) e = __expf(score - m);
    float l = e;
    #pragma unroll
    for (int off = 32; off >= 1; off >>= 1)
        l += __shfl_xor(l, off, 64);
    if (lane == 0) sRed[4 + wave] = l;
    __syncthreads();            // sS raw fully consumed (each slot by its owner)
    if (t < T) sS[t] = e;       // unnormalized weights (0 for masked)
    __syncthreads();
    l = sRed[4] + sRed[5] + sRed[6] + sRed[7];
    const float inv_l = __builtin_amdgcn_rcpf(l);

    // ---- Phase D: out[b][h] = sum_t w_t * K[t][h], from LDS bf16 ----
    const int h2i = tid & 31;          // column pair 2*h2i, 2*h2i+1
    const int c   = tid >> 5;          // 8 chunks of 25 positions
    float p0 = 0.f, p1 = 0.f;
    for (int t2 = c * 25; t2 < c * 25 + 25; ++t2) {
        const float w = sS[t2];
        const unsigned kk = *(const unsigned*)&sKb[t2 * KS1 + h2i * 2];
        p0 += w * bf2f((unsigned short)(kk & 0xffffu));
        p1 += w * bf2f((unsigned short)(kk >> 16));
    }
    sPart[c][h2i * 2 + 0] = p0;
    sPart[c][h2i * 2 + 1] = p1;
    __syncthreads();
    if (tid < H) {
        float s = 0.f;
        #pragma unroll
        for (int cc = 0; cc < 8; ++cc) s += sPart[cc][tid];
        out[b * H + tid] = s * inv_l;
    }
}

extern "C" void kernel_launch(void* const* d_in, const int* in_sizes, int n_in,
                              void* d_out, int out_size, void* d_ws, size_t ws_size,
                              hipStream_t stream) {
    const float* q    = (const float*)d_in[0];
    const float* keys = (const float*)d_in[1];
    const int*   lens = (const int*)d_in[2];
    const float* W1   = (const float*)d_in[3];
    const float* b1   = (const float*)d_in[4];
    const float* W2   = (const float*)d_in[5];
    const float* b2   = (const float*)d_in[6];
    const float* Wd   = (const float*)d_in[7];
    const float* bd   = (const float*)d_in[8];
    float* outp = (float*)d_out;

    din_mfma<<<BATCH, 256, 0, stream>>>(q, keys, lens, W1, b1, W2, b2, Wd, bd, outp);
}